// Round 6
// baseline (160.746 us; speedup 1.0000x reference)
//
#include <hip/hip_runtime.h>
#include <math.h>

#define SEQ  2048
#define ROWS 4096
#define D0   512
#define D1   64

typedef short bf8 __attribute__((ext_vector_type(8)));   // 8 bf16 = 4 VGPRs
typedef float f4  __attribute__((ext_vector_type(4)));   // MFMA acc

// fp32 -> bf16 hi/lo split (RNE)
__device__ __forceinline__ unsigned short f2bf(float f) {
    unsigned u = __float_as_uint(f);
    return (unsigned short)((u + 0x7fffu + ((u >> 16) & 1u)) >> 16);
}
__device__ __forceinline__ void hilo(float f, unsigned short& h, unsigned short& l) {
    h = f2bf(f);
    float fh = __uint_as_float((unsigned)h << 16);
    l = f2bf(f - fh);
}
__device__ __forceinline__ void cv4(unsigned short* dh, unsigned short* dl, int idx, float4 v) {
    ushort4 hv, lv;
    hilo(v.x, hv.x, lv.x); hilo(v.y, hv.y, lv.y);
    hilo(v.z, hv.z, lv.z); hilo(v.w, hv.w, lv.w);
    *(ushort4*)(dh + idx) = hv;
    *(ushort4*)(dl + idx) = lv;
}
__device__ __forceinline__ void cv4h(unsigned short* dh, int idx, float4 v) {
    ushort4 hv;
    hv.x = f2bf(v.x); hv.y = f2bf(v.y); hv.z = f2bf(v.z); hv.w = f2bf(v.w);
    *(ushort4*)(dh + idx) = hv;
}

// async global->LDS 16B (dest = wave-uniform base + lane*16)
__device__ __forceinline__ void async16(const void* g, void* l) {
    __builtin_amdgcn_global_load_lds(
        (const __attribute__((address_space(1))) unsigned int*)g,
        (__attribute__((address_space(3))) unsigned int*)l, 16, 0, 0);
}

// ---------------------------------------------------------------------------
// Conversion: x -> bf16 hi/lo planes; weights -> bf16 hi plane only (bf16x2);
// A1/A3 transpose.
// ---------------------------------------------------------------------------
__global__ __launch_bounds__(256) void convk(
        const float* __restrict__ x,  const float* __restrict__ W1,
        const float* __restrict__ M2, const float* __restrict__ R2,
        const float* __restrict__ W3, const float* __restrict__ R3,
        const float* __restrict__ A1, const float* __restrict__ A3,
        unsigned short* __restrict__ xh,  unsigned short* __restrict__ xl,
        unsigned short* __restrict__ W1h,
        unsigned short* __restrict__ C2h,
        unsigned short* __restrict__ C3h,
        float* __restrict__ A1T, float* __restrict__ A3T) {
    int c = blockIdx.x, tid = threadIdx.x;
    if (c < 1024) {                        // x: hi + lo
        int base = c * 2048 + tid * 4;
        cv4(xh, xl, base,        *(const float4*)(x + base));
        cv4(xh, xl, base + 1024, *(const float4*)(x + base + 1024));
    } else if (c < 1216) {                 // weights: hi only
        const float* src; unsigned short* dh; int off;
        if      (c < 1152) { src = W1; dh = W1h;         off = c - 1024; }
        else if (c < 1168) { src = M2; dh = C2h;         off = c - 1152; }
        else if (c < 1184) { src = R2; dh = C2h + 32768; off = c - 1168; }
        else if (c < 1200) { src = W3; dh = C3h;         off = c - 1184; }
        else               { src = R3; dh = C3h + 32768; off = c - 1200; }
        int base = off * 2048 + tid * 4;
        cv4h(dh, base,        *(const float4*)(src + base));
        cv4h(dh, base + 1024, *(const float4*)(src + base + 1024));
    } else {
        int gid = (c - 1216) * 256 + tid;     // 0..32767
        int i = gid >> 6, j = gid & 63;       // A (512 x 64)
        A1T[j * 512 + i] = A1[gid];
        A3T[j * 512 + i] = A3[gid];
    }
}

// ---------------------------------------------------------------------------
// bf16x2 MFMA GEMM, 128(M) x 64(N) tile, BK=64, 256 thr = 4 waves.
// A split hi+lo, W hi only:  C = (Ah+Al) @ Wh^T.
// XOR-swizzled LDS: chunk ch of row r at slot ch^(r&7), swizzle applied on
// the GLOBAL source index so global_load_lds dest stays wave-uniform+lane*16.
// Wave wv owns m-rows [wv*32,+32) (2 16-tiles) x all 4 n-tiles -> 2x4 accs.
// MFMA:ds_read = 32:16 per K-tile. LDS 40 KB -> 4 blocks/CU.
// grid: x = N/64, y = M/128, z = split-K (k0 = z*Ks, C += z*M*N).
// ---------------------------------------------------------------------------
__global__ __launch_bounds__(256, 4) void gemm128(
        const unsigned short* __restrict__ Ah, const unsigned short* __restrict__ Al,
        const unsigned short* __restrict__ Wh,
        float* __restrict__ C, int M, int N, int K, int Ks) {
    __shared__ __align__(16) unsigned short aH[8192], aL[8192], wH[4096];
    const int tid = threadIdx.x;
    const int wv  = tid >> 6;
    const int ln  = tid & 63;
    const int lm  = ln & 15;
    const int lq  = ln >> 4;
    const int bm  = blockIdx.y * 128;
    const int bn  = blockIdx.x * 64;
    const int k0  = blockIdx.z * Ks;
    C += (size_t)blockIdx.z * M * N;

    f4 acc[2][4] = {};

    for (int kt = 0; kt < Ks; kt += 64) {
        const int kg = k0 + kt;
        __syncthreads();
        // A planes: 1024 slots each (128 rows x 8 chunks), 4 slots/thread
#pragma unroll
        for (int i = 0; i < 4; ++i) {
            int slot = i * 256 + wv * 64 + ln;
            int row  = slot >> 3;
            int ch   = (slot & 7) ^ (row & 7);
            size_t go = (size_t)(bm + row) * K + kg + ch * 8;
            async16(Ah + go, aH + slot * 8);
            async16(Al + go, aL + slot * 8);
        }
        // W hi plane: 512 slots (64 rows x 8 chunks), 2 slots/thread
#pragma unroll
        for (int i = 0; i < 2; ++i) {
            int slot = i * 256 + wv * 64 + ln;
            int row  = slot >> 3;
            int ch   = (slot & 7) ^ (row & 7);
            size_t go = (size_t)(bn + row) * K + kg + ch * 8;
            async16(Wh + go, wH + slot * 8);
        }
        __syncthreads();

#pragma unroll
        for (int kk = 0; kk < 2; ++kk) {
            const int ck = kk * 4 + lq;          // 16B chunk index in k
            bf8 a_h[2], a_l[2], b_h[4];
#pragma unroll
            for (int t = 0; t < 2; ++t) {
                int r = wv * 32 + t * 16 + lm;
                a_h[t] = *(const bf8*)(aH + r * 64 + ((ck ^ (r & 7)) * 8));
                a_l[t] = *(const bf8*)(aL + r * 64 + ((ck ^ (r & 7)) * 8));
            }
#pragma unroll
            for (int u = 0; u < 4; ++u) {
                int rb = u * 16 + lm;
                b_h[u] = *(const bf8*)(wH + rb * 64 + ((ck ^ (rb & 7)) * 8));
            }
#pragma unroll
            for (int t = 0; t < 2; ++t)
#pragma unroll
                for (int u = 0; u < 4; ++u) {
                    acc[t][u] = __builtin_amdgcn_mfma_f32_16x16x32_bf16(a_h[t], b_h[u], acc[t][u], 0, 0, 0);
                    acc[t][u] = __builtin_amdgcn_mfma_f32_16x16x32_bf16(a_l[t], b_h[u], acc[t][u], 0, 0, 0);
                }
        }
    }

    // C/D layout (verified): col = lane&15, row = quad*4 + reg
#pragma unroll
    for (int t = 0; t < 2; ++t)
#pragma unroll
        for (int u = 0; u < 4; ++u) {
            int row = bm + wv * 32 + t * 16 + lq * 4;
            int col = bn + u * 16 + lm;
#pragma unroll
            for (int r = 0; r < 4; ++r)
                C[(size_t)(row + r) * N + col] = acc[t][u][r];
        }
}

// ---------------------------------------------------------------------------
// LN + rank-1 RN epilogue, one row per wave (as R4/R5, passed).
// ---------------------------------------------------------------------------
__global__ __launch_bounds__(256) void lnrn(
        const float* __restrict__ Y, const float* __restrict__ Y2, int ldy,
        const float* __restrict__ RES, int ldr,
        const float* __restrict__ g, const float* __restrict__ be,
        const float* __restrict__ Bb, const float* __restrict__ AaT,
        float* __restrict__ outf,
        unsigned short* __restrict__ outh, unsigned short* __restrict__ outl) {
    const int row = blockIdx.x * 4 + (threadIdx.x >> 6);
    const int l = threadIdx.x & 63;
    const int c = l * 8;
    const float* y = Y + (size_t)row * ldy + c;
    float4 y0 = *(const float4*)y;
    float4 y1 = *(const float4*)(y + 4);
    if (Y2) {
        const float* y2 = Y2 + (size_t)row * ldy + c;
        float4 p0 = *(const float4*)y2, p1 = *(const float4*)(y2 + 4);
        y0.x += p0.x; y0.y += p0.y; y0.z += p0.z; y0.w += p0.w;
        y1.x += p1.x; y1.y += p1.y; y1.z += p1.z; y1.w += p1.w;
    }
    float sum = y0.x + y0.y + y0.z + y0.w + y1.x + y1.y + y1.z + y1.w;
    float ssq = y0.x*y0.x + y0.y*y0.y + y0.z*y0.z + y0.w*y0.w
              + y1.x*y1.x + y1.y*y1.y + y1.z*y1.z + y1.w*y1.w;
#pragma unroll
    for (int m = 1; m < 64; m <<= 1) {
        sum += __shfl_xor(sum, m, 64);
        ssq += __shfl_xor(ssq, m, 64);
    }
    float mean = sum * (1.0f / 512.0f);
    float var  = ssq * (1.0f / 512.0f) - mean * mean;
    float rstd = rsqrtf(var + 1e-5f);
    float4 g0 = *(const float4*)(g + c),  g1v = *(const float4*)(g + c + 4);
    float4 e0 = *(const float4*)(be + c), e1  = *(const float4*)(be + c + 4);
    float4 n0, n1;
    n0.x = (y0.x - mean) * rstd * g0.x  + e0.x;
    n0.y = (y0.y - mean) * rstd * g0.y  + e0.y;
    n0.z = (y0.z - mean) * rstd * g0.z  + e0.z;
    n0.w = (y0.w - mean) * rstd * g0.w  + e0.w;
    n1.x = (y1.x - mean) * rstd * g1v.x + e1.x;
    n1.y = (y1.y - mean) * rstd * g1v.y + e1.y;
    n1.z = (y1.z - mean) * rstd * g1v.z + e1.z;
    n1.w = (y1.w - mean) * rstd * g1v.w + e1.w;
    const int jm = row & 63;
    const float* bb = Bb + jm * D0 + c;
    float4 b0 = *(const float4*)bb, b1v = *(const float4*)(bb + 4);
    float p = n0.x*b0.x + n0.y*b0.y + n0.z*b0.z + n0.w*b0.w
            + n1.x*b1v.x + n1.y*b1v.y + n1.z*b1v.z + n1.w*b1v.w;
#pragma unroll
    for (int m = 1; m < 64; m <<= 1) p += __shfl_xor(p, m, 64);
    const float* av = AaT + jm * D0 + c;
    float4 a0 = *(const float4*)av, a1 = *(const float4*)(av + 4);
    const float* rs = RES + (size_t)row * ldr + c;
    float4 r0 = *(const float4*)rs, r1 = *(const float4*)(rs + 4);
    float4 v0, v1;
    v0.x = p*a0.x + r0.x; v0.y = p*a0.y + r0.y; v0.z = p*a0.z + r0.z; v0.w = p*a0.w + r0.w;
    v1.x = p*a1.x + r1.x; v1.y = p*a1.y + r1.y; v1.z = p*a1.z + r1.z; v1.w = p*a1.w + r1.w;
    if (outf) {
        *(float4*)(outf + (size_t)row * D0 + c)     = v0;
        *(float4*)(outf + (size_t)row * D0 + c + 4) = v1;
    } else {
        ushort4 h0, l0, h1, l1;
        hilo(v0.x, h0.x, l0.x); hilo(v0.y, h0.y, l0.y);
        hilo(v0.z, h0.z, l0.z); hilo(v0.w, h0.w, l0.w);
        hilo(v1.x, h1.x, l1.x); hilo(v1.y, h1.y, l1.y);
        hilo(v1.z, h1.z, l1.z); hilo(v1.w, h1.w, l1.w);
        *(ushort4*)(outh + (size_t)row * D0 + c)     = h0;
        *(ushort4*)(outl + (size_t)row * D0 + c)     = l0;
        *(ushort4*)(outh + (size_t)row * D0 + c + 4) = h1;
        *(ushort4*)(outl + (size_t)row * D0 + c + 4) = l1;
    }
}

// ---------------------------------------------------------------------------
// lnt: sum 4 split-K partials of C2, LN the y-half -> t, sum residual -> rsum.
// ---------------------------------------------------------------------------
#define C2S 524288
__global__ __launch_bounds__(256) void lnt(
        const float* __restrict__ C2, const float* __restrict__ g2,
        const float* __restrict__ b2,
        float* __restrict__ t, float* __restrict__ rsum) {
    const int r = blockIdx.x * 4 + (threadIdx.x >> 6);   // 0..4095
    const int j = threadIdx.x & 63;
    size_t base = (size_t)r * 128 + j;
    float v = 0.f, rv = 0.f;
#pragma unroll
    for (int z = 0; z < 4; ++z) {
        v  += C2[(size_t)z * C2S + base];
        rv += C2[(size_t)z * C2S + base + 64];
    }
    float sum = v, ssq = v * v;
#pragma unroll
    for (int m = 1; m < 64; m <<= 1) {
        sum += __shfl_xor(sum, m, 64);
        ssq += __shfl_xor(ssq, m, 64);
    }
    float mean = sum * (1.0f / 64.0f);
    float var  = ssq * (1.0f / 64.0f) - mean * mean;
    float rstd = rsqrtf(var + 1e-5f);
    t[r * 64 + j]    = (v - mean) * rstd * g2[j] + b2[j];
    rsum[r * 64 + j] = rv;
}

// ---------------------------------------------------------------------------
// tsk2: Chebyshev-recurrence TS layer (as R5, passed).
// ---------------------------------------------------------------------------
__global__ __launch_bounds__(256) void tsk2(
        const float* __restrict__ t, const float* __restrict__ rsum,
        const float* __restrict__ P,
        unsigned short* __restrict__ Hh, unsigned short* __restrict__ Hl) {
    const int bid = blockIdx.x;
    const int i   = bid >> 3;
    const int sg  = bid & 7;
    const int w   = threadIdx.x >> 6;
    const int ln  = threadIdx.x & 63;       // j
    const int s0  = sg * 256 + w * 64;
    const int idx = i * 64 + ln;
    const float* pp = P + idx * 8;
    const float sf0 = (float)s0;

    float k2c[8], ca[8], cb[8];
#pragma unroll
    for (int g = 0; g < 8; ++g) {
        float pf   = (float)(idx * 8 + g + 2);
        float invp = __builtin_amdgcn_rcpf(pf);
        k2c[g] = 2.0f * __builtin_amdgcn_cosf(invp);     // 2*cos(2*pi/p)
        float q0 = floorf(sf0 * invp);
        float r0 = fmaf(-q0, pf, sf0);
        float f0 = r0 * invp; f0 -= floorf(f0);
        float c0 = __builtin_amdgcn_cosf(f0);            // cos(2*pi*s0/p)
        float sf1 = sf0 + 1.0f;
        float q1 = floorf(sf1 * invp);
        float r1 = fmaf(-q1, pf, sf1);
        float f1 = r1 * invp; f1 -= floorf(f1);
        float c1 = __builtin_amdgcn_cosf(f1);            // cos(2*pi*(s0+1)/p)
        float Pv = pp[g];
        ca[g] = Pv * c0;
        cb[g] = Pv * c1;
    }

    const int tb = s0 * 64 + ln;
    float t0c = t[tb], t1c = t[131072 + tb];
    float res0 = 0.f, res1 = 0.f;

    for (int st = 0; st < 64; st += 2) {
        float t0n  = t[tb + (st + 1) * 64];
        float t1n  = t[131072 + tb + (st + 1) * 64];
        float ws = ((ca[0] + ca[1]) + (ca[2] + ca[3]))
                 + ((ca[4] + ca[5]) + (ca[6] + ca[7]));
#pragma unroll
        for (int g = 0; g < 8; ++g) ca[g] = fmaf(k2c[g], cb[g], -ca[g]);
        float v0 = ws * t0c, v1 = ws * t1c;
#pragma unroll
        for (int m = 1; m < 64; m <<= 1) {
            v0 += __shfl_xor(v0, m, 64);
            v1 += __shfl_xor(v1, m, 64);
        }
        res0 = (ln == st) ? v0 : res0;
        res1 = (ln == st) ? v1 : res1;
        float t0n2 = t[tb + (st + 2) * 64];
        float t1n2 = t[131072 + tb + (st + 2) * 64];
        float ws2 = ((cb[0] + cb[1]) + (cb[2] + cb[3]))
                  + ((cb[4] + cb[5]) + (cb[6] + cb[7]));
#pragma unroll
        for (int g = 0; g < 8; ++g) cb[g] = fmaf(k2c[g], ca[g], -cb[g]);
        float v0b = ws2 * t0n, v1b = ws2 * t1n;
#pragma unroll
        for (int m = 1; m < 64; m <<= 1) {
            v0b += __shfl_xor(v0b, m, 64);
            v1b += __shfl_xor(v1b, m, 64);
        }
        res0 = (ln == st + 1) ? v0b : res0;
        res1 = (ln == st + 1) ? v1b : res1;
        t0c = t0n2; t1c = t1n2;
    }

    const int s = s0 + ln;
    {
        float v = res0 + rsum[(size_t)s * 64 + i];
        unsigned short h, l; hilo(v, h, l);
        Hh[(size_t)s * 64 + i] = h; Hl[(size_t)s * 64 + i] = l;
        float v1e = res1 + rsum[(size_t)(SEQ + s) * 64 + i];
        hilo(v1e, h, l);
        Hh[(size_t)(SEQ + s) * 64 + i] = h; Hl[(size_t)(SEQ + s) * 64 + i] = l;
    }
}

// ---------------------------------------------------------------------------
extern "C" void kernel_launch(void* const* d_in, const int* in_sizes, int n_in,
                              void* d_out, int out_size, void* d_ws, size_t ws_size,
                              hipStream_t stream) {
    const float* x  = (const float*)d_in[0];
    const float* W1 = (const float*)d_in[1];
    const float* g1 = (const float*)d_in[2];
    const float* b1 = (const float*)d_in[3];
    const float* A1 = (const float*)d_in[4];
    const float* B1 = (const float*)d_in[5];
    const float* M2 = (const float*)d_in[6];
    const float* g2 = (const float*)d_in[7];
    const float* b2 = (const float*)d_in[8];
    const float* P2 = (const float*)d_in[9];
    const float* R2 = (const float*)d_in[10];
    const float* W3 = (const float*)d_in[11];
    const float* g3 = (const float*)d_in[12];
    const float* b3 = (const float*)d_in[13];
    const float* A3 = (const float*)d_in[14];
    const float* B3 = (const float*)d_in[15];
    const float* R3 = (const float*)d_in[16];

    float* ws = (float*)d_ws;
    float* C1   = ws;                   // 2 x 2,097,152 = 4,194,304
    float* C2   = ws + 4194304;         // 4 x 524,288   = 2,097,152
    float* C3   = ws + 6291456;         // 4,194,304
    float* t    = ws + 10485760;        // 262,144 (4096 x 64)
    float* rsum = ws + 10747904;        // 262,144 (must follow t: overrun pad)
    float* A1T  = ws + 11010048;        // 32,768
    float* A3T  = ws + 11042816;        // 32,768
    unsigned short* us = (unsigned short*)(ws + 11075584);
    unsigned short* xh   = us;                  // 2,097,152 each
    unsigned short* xl   = us + 2097152;
    unsigned short* h1h  = us + 4194304;
    unsigned short* h1l  = us + 6291456;
    unsigned short* W1h  = us + 8388608;        // 262,144
    unsigned short* Wc2h = us + 8650752;        // 65,536 (128 x 512)
    unsigned short* Wc3h = us + 8716288;        // 65,536 (1024 x 64)
    unsigned short* h2h  = us + 8781824;        // 262,144 each (4096 x 64)
    unsigned short* h2l  = us + 9043968;

    dim3 blk(256);

    // 0) convert (x: hi+lo; weights: hi) + transpose A1/A3
    convk<<<1344, blk, 0, stream>>>(x, W1, M2, R2, W3, R3, A1, A3,
                                    xh, xl, W1h, Wc2h, Wc3h, A1T, A3T);

    // 1) C1 = x @ W1^T (split-K=2 -> 512 blocks); h1 = RN(C1)+x -> planes
    gemm128<<<dim3(8, 32, 2), blk, 0, stream>>>(xh, xl, W1h, C1, ROWS, 512, 512, 256);
    lnrn<<<1024, blk, 0, stream>>>(C1, C1 + 2097152, 512, x, 512, g1, b1, B1, A1T,
                                   nullptr, h1h, h1l);

    // 2) C2 = h1 @ [M2;R2]^T (split-K=4 -> 256 blocks); t/rsum; h2 = TS
    gemm128<<<dim3(2, 32, 4), blk, 0, stream>>>(h1h, h1l, Wc2h, C2, ROWS, 128, 512, 128);
    lnt<<<1024, blk, 0, stream>>>(C2, g2, b2, t, rsum);
    tsk2<<<512, blk, 0, stream>>>(t, rsum, P2, h2h, h2l);

    // 3) C3 = h2 @ [W3;R3]^T (512 blocks); out = RN(C3[:,:512]) + C3[:,512:]
    gemm128<<<dim3(16, 32, 1), blk, 0, stream>>>(h2h, h2l, Wc3h, C3, ROWS, 1024, 64, 64);
    lnrn<<<1024, blk, 0, stream>>>(C3, nullptr, 1024, C3 + 512, 1024, g3, b3, B3, A3T,
                                   (float*)d_out, nullptr, nullptr);
}

// Round 7
// 151.084 us; speedup vs baseline: 1.0640x; 1.0640x over previous
//
#include <hip/hip_runtime.h>
#include <math.h>

#define SEQ  2048
#define ROWS 4096
#define D0   512
#define D1   64

typedef short bf8 __attribute__((ext_vector_type(8)));   // 8 bf16 = 4 VGPRs
typedef float f4  __attribute__((ext_vector_type(4)));   // MFMA acc

// fp32 -> bf16 (RNE) and hi/lo split
__device__ __forceinline__ unsigned short f2bf(float f) {
    unsigned u = __float_as_uint(f);
    return (unsigned short)((u + 0x7fffu + ((u >> 16) & 1u)) >> 16);
}
__device__ __forceinline__ float bf2f(unsigned short u) {
    return __uint_as_float((unsigned)u << 16);
}
__device__ __forceinline__ void hilo(float f, unsigned short& h, unsigned short& l) {
    h = f2bf(f);
    float fh = bf2f(h);
    l = f2bf(f - fh);
}
__device__ __forceinline__ void cv4h(unsigned short* dh, int idx, float4 v) {
    ushort4 hv;
    hv.x = f2bf(v.x); hv.y = f2bf(v.y); hv.z = f2bf(v.z); hv.w = f2bf(v.w);
    *(ushort4*)(dh + idx) = hv;
}

// async global->LDS 16B (dest = wave-uniform base + lane*16)
__device__ __forceinline__ void async16(const void* g, void* l) {
    __builtin_amdgcn_global_load_lds(
        (const __attribute__((address_space(1))) unsigned int*)g,
        (__attribute__((address_space(3))) unsigned int*)l, 16, 0, 0);
}

// ---------------------------------------------------------------------------
// Conversion: x + weights -> bf16 hi planes only; A1/A3 transpose.
// (x-lo dropped: its contribution is damped to ~2e-4 by the rank-1 scal*A path
//  and the residual uses fp32 x directly.)
// ---------------------------------------------------------------------------
__global__ __launch_bounds__(256) void convk(
        const float* __restrict__ x,  const float* __restrict__ W1,
        const float* __restrict__ M2, const float* __restrict__ R2,
        const float* __restrict__ W3, const float* __restrict__ R3,
        const float* __restrict__ A1, const float* __restrict__ A3,
        unsigned short* __restrict__ xh,
        unsigned short* __restrict__ W1h,
        unsigned short* __restrict__ C2h,
        unsigned short* __restrict__ C3h,
        float* __restrict__ A1T, float* __restrict__ A3T) {
    int c = blockIdx.x, tid = threadIdx.x;
    if (c < 1216) {
        const float* src; unsigned short* dh; int off;
        if      (c < 1024) { src = x;  dh = xh;          off = c; }
        else if (c < 1152) { src = W1; dh = W1h;         off = c - 1024; }
        else if (c < 1168) { src = M2; dh = C2h;         off = c - 1152; }
        else if (c < 1184) { src = R2; dh = C2h + 32768; off = c - 1168; }
        else if (c < 1200) { src = W3; dh = C3h;         off = c - 1184; }
        else               { src = R3; dh = C3h + 32768; off = c - 1200; }
        int base = off * 2048 + tid * 4;
        cv4h(dh, base,        *(const float4*)(src + base));
        cv4h(dh, base + 1024, *(const float4*)(src + base + 1024));
    } else {
        int gid = (c - 1216) * 256 + tid;     // 0..32767
        int i = gid >> 6, j = gid & 63;       // A (512 x 64)
        A1T[j * 512 + i] = A1[gid];
        A3T[j * 512 + i] = A3[gid];
    }
}

// ---------------------------------------------------------------------------
// MFMA GEMM, 128(M) x 64(N) tile, BK=64, 256 thr = 4 waves.
// ALO: A has a lo plane (bf16x2) or hi only (bf16x1).
// OM:  0 = fp32 C (split-K partials);  1 = bf16 C (split-K partials);
//      2 = mixed (bn<512 -> bf16 at ld 512; bn>=512 -> fp32 at ld 512).
// XOR-swizzled LDS (swizzle on global source idx; dest stays wave-uniform).
// ---------------------------------------------------------------------------
template<bool ALO, int OM>
__global__ __launch_bounds__(256, 4) void gemm128t(
        const unsigned short* __restrict__ Ah, const unsigned short* __restrict__ Al,
        const unsigned short* __restrict__ Wh,
        float* __restrict__ Cf, unsigned short* __restrict__ Cb,
        int M, int N, int K, int Ks) {
    __shared__ __align__(16) unsigned short aH[8192];
    __shared__ __align__(16) unsigned short aL[ALO ? 8192 : 16];
    __shared__ __align__(16) unsigned short wH[4096];
    const int tid = threadIdx.x;
    const int wv  = tid >> 6;
    const int ln  = tid & 63;
    const int lm  = ln & 15;
    const int lq  = ln >> 4;
    const int bm  = blockIdx.y * 128;
    const int bn  = blockIdx.x * 64;
    const int k0  = blockIdx.z * Ks;

    f4 acc[2][4] = {};

    for (int kt = 0; kt < Ks; kt += 64) {
        const int kg = k0 + kt;
        __syncthreads();
#pragma unroll
        for (int i = 0; i < 4; ++i) {
            int slot = i * 256 + wv * 64 + ln;
            int row  = slot >> 3;
            int ch   = (slot & 7) ^ (row & 7);
            size_t go = (size_t)(bm + row) * K + kg + ch * 8;
            async16(Ah + go, aH + slot * 8);
            if constexpr (ALO) async16(Al + go, aL + slot * 8);
        }
#pragma unroll
        for (int i = 0; i < 2; ++i) {
            int slot = i * 256 + wv * 64 + ln;
            int row  = slot >> 3;
            int ch   = (slot & 7) ^ (row & 7);
            size_t go = (size_t)(bn + row) * K + kg + ch * 8;
            async16(Wh + go, wH + slot * 8);
        }
        __syncthreads();

#pragma unroll
        for (int kk = 0; kk < 2; ++kk) {
            const int ck = kk * 4 + lq;          // 16B chunk index in k
            bf8 a_h[2], a_l[2], b_h[4];
#pragma unroll
            for (int t = 0; t < 2; ++t) {
                int r = wv * 32 + t * 16 + lm;
                a_h[t] = *(const bf8*)(aH + r * 64 + ((ck ^ (r & 7)) * 8));
                if constexpr (ALO)
                    a_l[t] = *(const bf8*)(aL + r * 64 + ((ck ^ (r & 7)) * 8));
            }
#pragma unroll
            for (int u = 0; u < 4; ++u) {
                int rb = u * 16 + lm;
                b_h[u] = *(const bf8*)(wH + rb * 64 + ((ck ^ (rb & 7)) * 8));
            }
#pragma unroll
            for (int t = 0; t < 2; ++t)
#pragma unroll
                for (int u = 0; u < 4; ++u) {
                    acc[t][u] = __builtin_amdgcn_mfma_f32_16x16x32_bf16(a_h[t], b_h[u], acc[t][u], 0, 0, 0);
                    if constexpr (ALO)
                        acc[t][u] = __builtin_amdgcn_mfma_f32_16x16x32_bf16(a_l[t], b_h[u], acc[t][u], 0, 0, 0);
                }
        }
    }

    // C/D layout (verified): col = lane&15, row = quad*4 + reg
#pragma unroll
    for (int t = 0; t < 2; ++t)
#pragma unroll
        for (int u = 0; u < 4; ++u) {
            int row = bm + wv * 32 + t * 16 + lq * 4;
            int col = bn + u * 16 + lm;
#pragma unroll
            for (int r = 0; r < 4; ++r) {
                float v = acc[t][u][r];
                if constexpr (OM == 0) {
                    Cf[(size_t)blockIdx.z * M * N + (size_t)(row + r) * N + col] = v;
                } else if constexpr (OM == 1) {
                    Cb[(size_t)blockIdx.z * M * N + (size_t)(row + r) * N + col] = f2bf(v);
                } else {
                    if (col < 512) Cb[(size_t)(row + r) * 512 + col] = f2bf(v);
                    else           Cf[(size_t)(row + r) * 512 + col - 512] = v;
                }
            }
        }
}

// ---------------------------------------------------------------------------
// LN + rank-1 RN epilogue, one row per wave. Y = bf16 plane(s) (Yb1 optional
// second split-K partial). RES fp32 (ld 512). Out fp32 or bf16 hi/lo planes.
// ---------------------------------------------------------------------------
__global__ __launch_bounds__(256) void lnrn(
        const unsigned short* __restrict__ Yb0,
        const unsigned short* __restrict__ Yb1,
        const float* __restrict__ RES,
        const float* __restrict__ g, const float* __restrict__ be,
        const float* __restrict__ Bb, const float* __restrict__ AaT,
        float* __restrict__ outf,
        unsigned short* __restrict__ outh, unsigned short* __restrict__ outl) {
    const int row = blockIdx.x * 4 + (threadIdx.x >> 6);
    const int l = threadIdx.x & 63;
    const int c = l * 8;
    ushort4 ua = *(const ushort4*)(Yb0 + (size_t)row * D0 + c);
    ushort4 ub = *(const ushort4*)(Yb0 + (size_t)row * D0 + c + 4);
    float4 y0, y1;
    y0.x = bf2f(ua.x); y0.y = bf2f(ua.y); y0.z = bf2f(ua.z); y0.w = bf2f(ua.w);
    y1.x = bf2f(ub.x); y1.y = bf2f(ub.y); y1.z = bf2f(ub.z); y1.w = bf2f(ub.w);
    if (Yb1) {
        ushort4 va = *(const ushort4*)(Yb1 + (size_t)row * D0 + c);
        ushort4 vb = *(const ushort4*)(Yb1 + (size_t)row * D0 + c + 4);
        y0.x += bf2f(va.x); y0.y += bf2f(va.y); y0.z += bf2f(va.z); y0.w += bf2f(va.w);
        y1.x += bf2f(vb.x); y1.y += bf2f(vb.y); y1.z += bf2f(vb.z); y1.w += bf2f(vb.w);
    }
    float sum = y0.x + y0.y + y0.z + y0.w + y1.x + y1.y + y1.z + y1.w;
    float ssq = y0.x*y0.x + y0.y*y0.y + y0.z*y0.z + y0.w*y0.w
              + y1.x*y1.x + y1.y*y1.y + y1.z*y1.z + y1.w*y1.w;
#pragma unroll
    for (int m = 1; m < 64; m <<= 1) {
        sum += __shfl_xor(sum, m, 64);
        ssq += __shfl_xor(ssq, m, 64);
    }
    float mean = sum * (1.0f / 512.0f);
    float var  = ssq * (1.0f / 512.0f) - mean * mean;
    float rstd = rsqrtf(var + 1e-5f);
    float4 g0 = *(const float4*)(g + c),  g1v = *(const float4*)(g + c + 4);
    float4 e0 = *(const float4*)(be + c), e1  = *(const float4*)(be + c + 4);
    float4 n0, n1;
    n0.x = (y0.x - mean) * rstd * g0.x  + e0.x;
    n0.y = (y0.y - mean) * rstd * g0.y  + e0.y;
    n0.z = (y0.z - mean) * rstd * g0.z  + e0.z;
    n0.w = (y0.w - mean) * rstd * g0.w  + e0.w;
    n1.x = (y1.x - mean) * rstd * g1v.x + e1.x;
    n1.y = (y1.y - mean) * rstd * g1v.y + e1.y;
    n1.z = (y1.z - mean) * rstd * g1v.z + e1.z;
    n1.w = (y1.w - mean) * rstd * g1v.w + e1.w;
    const int jm = row & 63;
    const float* bb = Bb + jm * D0 + c;
    float4 b0 = *(const float4*)bb, b1v = *(const float4*)(bb + 4);
    float p = n0.x*b0.x + n0.y*b0.y + n0.z*b0.z + n0.w*b0.w
            + n1.x*b1v.x + n1.y*b1v.y + n1.z*b1v.z + n1.w*b1v.w;
#pragma unroll
    for (int m = 1; m < 64; m <<= 1) p += __shfl_xor(p, m, 64);
    const float* av = AaT + jm * D0 + c;
    float4 a0 = *(const float4*)av, a1 = *(const float4*)(av + 4);
    const float* rs = RES + (size_t)row * D0 + c;
    float4 r0 = *(const float4*)rs, r1 = *(const float4*)(rs + 4);
    float4 v0, v1;
    v0.x = p*a0.x + r0.x; v0.y = p*a0.y + r0.y; v0.z = p*a0.z + r0.z; v0.w = p*a0.w + r0.w;
    v1.x = p*a1.x + r1.x; v1.y = p*a1.y + r1.y; v1.z = p*a1.z + r1.z; v1.w = p*a1.w + r1.w;
    if (outf) {
        *(float4*)(outf + (size_t)row * D0 + c)     = v0;
        *(float4*)(outf + (size_t)row * D0 + c + 4) = v1;
    } else {
        ushort4 h0, l0, h1, l1;
        hilo(v0.x, h0.x, l0.x); hilo(v0.y, h0.y, l0.y);
        hilo(v0.z, h0.z, l0.z); hilo(v0.w, h0.w, l0.w);
        hilo(v1.x, h1.x, l1.x); hilo(v1.y, h1.y, l1.y);
        hilo(v1.z, h1.z, l1.z); hilo(v1.w, h1.w, l1.w);
        *(ushort4*)(outh + (size_t)row * D0 + c)     = h0;
        *(ushort4*)(outl + (size_t)row * D0 + c)     = l0;
        *(ushort4*)(outh + (size_t)row * D0 + c + 4) = h1;
        *(ushort4*)(outl + (size_t)row * D0 + c + 4) = l1;
    }
}

// ---------------------------------------------------------------------------
// lnt: sum 4 split-K partials of C2, LN the y-half -> t, sum residual -> rsum.
// ---------------------------------------------------------------------------
#define C2S 524288
__global__ __launch_bounds__(256) void lnt(
        const float* __restrict__ C2, const float* __restrict__ g2,
        const float* __restrict__ b2,
        float* __restrict__ t, float* __restrict__ rsum) {
    const int r = blockIdx.x * 4 + (threadIdx.x >> 6);   // 0..4095
    const int j = threadIdx.x & 63;
    size_t base = (size_t)r * 128 + j;
    float v = 0.f, rv = 0.f;
#pragma unroll
    for (int z = 0; z < 4; ++z) {
        v  += C2[(size_t)z * C2S + base];
        rv += C2[(size_t)z * C2S + base + 64];
    }
    float sum = v, ssq = v * v;
#pragma unroll
    for (int m = 1; m < 64; m <<= 1) {
        sum += __shfl_xor(sum, m, 64);
        ssq += __shfl_xor(ssq, m, 64);
    }
    float mean = sum * (1.0f / 64.0f);
    float var  = ssq * (1.0f / 64.0f) - mean * mean;
    float rstd = rsqrtf(var + 1e-5f);
    t[r * 64 + j]    = (v - mean) * rstd * g2[j] + b2[j];
    rsum[r * 64 + j] = rv;
}

// ---------------------------------------------------------------------------
// tsk2: Chebyshev-recurrence TS layer (verified R5/R6).
// ---------------------------------------------------------------------------
__global__ __launch_bounds__(256) void tsk2(
        const float* __restrict__ t, const float* __restrict__ rsum,
        const float* __restrict__ P,
        unsigned short* __restrict__ Hh, unsigned short* __restrict__ Hl) {
    const int bid = blockIdx.x;
    const int i   = bid >> 3;
    const int sg  = bid & 7;
    const int w   = threadIdx.x >> 6;
    const int ln  = threadIdx.x & 63;       // j
    const int s0  = sg * 256 + w * 64;
    const int idx = i * 64 + ln;
    const float* pp = P + idx * 8;
    const float sf0 = (float)s0;

    float k2c[8], ca[8], cb[8];
#pragma unroll
    for (int g = 0; g < 8; ++g) {
        float pf   = (float)(idx * 8 + g + 2);
        float invp = __builtin_amdgcn_rcpf(pf);
        k2c[g] = 2.0f * __builtin_amdgcn_cosf(invp);     // 2*cos(2*pi/p)
        float q0 = floorf(sf0 * invp);
        float r0 = fmaf(-q0, pf, sf0);
        float f0 = r0 * invp; f0 -= floorf(f0);
        float c0 = __builtin_amdgcn_cosf(f0);
        float sf1 = sf0 + 1.0f;
        float q1 = floorf(sf1 * invp);
        float r1 = fmaf(-q1, pf, sf1);
        float f1 = r1 * invp; f1 -= floorf(f1);
        float c1 = __builtin_amdgcn_cosf(f1);
        float Pv = pp[g];
        ca[g] = Pv * c0;
        cb[g] = Pv * c1;
    }

    const int tb = s0 * 64 + ln;
    float t0c = t[tb], t1c = t[131072 + tb];
    float res0 = 0.f, res1 = 0.f;

    for (int st = 0; st < 64; st += 2) {
        float t0n  = t[tb + (st + 1) * 64];
        float t1n  = t[131072 + tb + (st + 1) * 64];
        float ws = ((ca[0] + ca[1]) + (ca[2] + ca[3]))
                 + ((ca[4] + ca[5]) + (ca[6] + ca[7]));
#pragma unroll
        for (int g = 0; g < 8; ++g) ca[g] = fmaf(k2c[g], cb[g], -ca[g]);
        float v0 = ws * t0c, v1 = ws * t1c;
#pragma unroll
        for (int m = 1; m < 64; m <<= 1) {
            v0 += __shfl_xor(v0, m, 64);
            v1 += __shfl_xor(v1, m, 64);
        }
        res0 = (ln == st) ? v0 : res0;
        res1 = (ln == st) ? v1 : res1;
        float t0n2 = t[tb + (st + 2) * 64];
        float t1n2 = t[131072 + tb + (st + 2) * 64];
        float ws2 = ((cb[0] + cb[1]) + (cb[2] + cb[3]))
                  + ((cb[4] + cb[5]) + (cb[6] + cb[7]));
#pragma unroll
        for (int g = 0; g < 8; ++g) cb[g] = fmaf(k2c[g], ca[g], -cb[g]);
        float v0b = ws2 * t0n, v1b = ws2 * t1n;
#pragma unroll
        for (int m = 1; m < 64; m <<= 1) {
            v0b += __shfl_xor(v0b, m, 64);
            v1b += __shfl_xor(v1b, m, 64);
        }
        res0 = (ln == st + 1) ? v0b : res0;
        res1 = (ln == st + 1) ? v1b : res1;
        t0c = t0n2; t1c = t1n2;
    }

    const int s = s0 + ln;
    {
        float v = res0 + rsum[(size_t)s * 64 + i];
        unsigned short h, l; hilo(v, h, l);
        Hh[(size_t)s * 64 + i] = h; Hl[(size_t)s * 64 + i] = l;
        float v1e = res1 + rsum[(size_t)(SEQ + s) * 64 + i];
        hilo(v1e, h, l);
        Hh[(size_t)(SEQ + s) * 64 + i] = h; Hl[(size_t)(SEQ + s) * 64 + i] = l;
    }
}

// ---------------------------------------------------------------------------
extern "C" void kernel_launch(void* const* d_in, const int* in_sizes, int n_in,
                              void* d_out, int out_size, void* d_ws, size_t ws_size,
                              hipStream_t stream) {
    const float* x  = (const float*)d_in[0];
    const float* W1 = (const float*)d_in[1];
    const float* g1 = (const float*)d_in[2];
    const float* b1 = (const float*)d_in[3];
    const float* A1 = (const float*)d_in[4];
    const float* B1 = (const float*)d_in[5];
    const float* M2 = (const float*)d_in[6];
    const float* g2 = (const float*)d_in[7];
    const float* b2 = (const float*)d_in[8];
    const float* P2 = (const float*)d_in[9];
    const float* R2 = (const float*)d_in[10];
    const float* W3 = (const float*)d_in[11];
    const float* g3 = (const float*)d_in[12];
    const float* b3 = (const float*)d_in[13];
    const float* A3 = (const float*)d_in[14];
    const float* B3 = (const float*)d_in[15];
    const float* R3 = (const float*)d_in[16];

    float* ws = (float*)d_ws;
    float* C2   = ws;                  // 4 x 524,288 = 2,097,152
    float* C3r  = ws + 2097152;        // 2,097,152 (4096 x 512 fp32 residual)
    float* t    = ws + 4194304;        // 262,144
    float* rsum = ws + 4456448;        // 262,144 (must follow t: overrun pad)
    float* A1T  = ws + 4718592;        // 32,768
    float* A3T  = ws + 4751360;        // 32,768
    unsigned short* us = (unsigned short*)(ws + 4784128);
    unsigned short* xh   = us;                  // 2,097,152
    unsigned short* h1h  = us + 2097152;        // 2,097,152
    unsigned short* h1l  = us + 4194304;        // 2,097,152
    unsigned short* W1h  = us + 6291456;        // 262,144
    unsigned short* Wc2h = us + 6553600;        // 65,536 (128 x 512)
    unsigned short* Wc3h = us + 6619136;        // 65,536 (1024 x 64)
    unsigned short* h2h  = us + 6684672;        // 262,144
    unsigned short* h2l  = us + 6946816;        // 262,144
    unsigned short* C1b  = us + 7208960;        // 2 x 2,097,152 (bf16 partials)
    unsigned short* C3n  = us + 11403264;       // 2,097,152 (4096 x 512 bf16)

    dim3 blk(256);

    // 0) convert (all hi-only) + transpose A1/A3
    convk<<<1344, blk, 0, stream>>>(x, W1, M2, R2, W3, R3, A1, A3,
                                    xh, W1h, Wc2h, Wc3h, A1T, A3T);

    // 1) C1b = x @ W1^T (bf16x1, split-K=2, bf16 partials); h1 = RN + x
    gemm128t<false, 1><<<dim3(8, 32, 2), blk, 0, stream>>>(
        xh, xh, W1h, nullptr, C1b, ROWS, 512, 512, 256);
    lnrn<<<1024, blk, 0, stream>>>(C1b, C1b + (size_t)ROWS * 512, x,
                                   g1, b1, B1, A1T, nullptr, h1h, h1l);

    // 2) C2 = h1 @ [M2;R2]^T (bf16x2, split-K=4, fp32 partials); t/rsum; TS
    gemm128t<true, 0><<<dim3(2, 32, 4), blk, 0, stream>>>(
        h1h, h1l, Wc2h, C2, nullptr, ROWS, 128, 512, 128);
    lnt<<<1024, blk, 0, stream>>>(C2, g2, b2, t, rsum);
    tsk2<<<512, blk, 0, stream>>>(t, rsum, P2, h2h, h2l);

    // 3) C3 = h2 @ [W3;R3]^T (bf16x2, mixed out: LN-half bf16, residual fp32)
    gemm128t<true, 2><<<dim3(16, 32, 1), blk, 0, stream>>>(
        h2h, h2l, Wc3h, C3r, C3n, ROWS, 1024, 64, 64);
    lnrn<<<1024, blk, 0, stream>>>(C3n, nullptr, C3r, g3, b3, B3, A3T,
                                   (float*)d_out, nullptr, nullptr);
}